// Round 12
// baseline (5371.024 us; speedup 1.0000x reference)
//
#include <hip/hip_runtime.h>
#include <float.h>
#include <math.h>

// ---------------- problem constants ----------------
#define M_ROWS 6272        // 8*28*28 rows of f
#define N_BANK 16384
#define K_DIM  1024
#define HW     784         // 28*28
#define CHW    802816      // 1024*784 (per-batch stride in features)
#define OUT_NORM_OFF 6422528
#define OUT_STD_OFF  6428800
#define N_ELEMS 6422528    // 6272*1024

#define DELTA 0.5f         // bf16-scan ambiguity margin on s (≈4 sigma of bf16 dot fuzz)
#define JSPLIT 32
#define JCHUNK (N_BANK / JSPLIT)   // 512
#define CAP 1024           // max refined rows (expect ~100-300 at DELTA=0.5)

// scratch layout (float offsets in d_out's noised region; all consumed before noise kernel)
#define WS_SIDX 0                  // 6272 ints
#define WS_INFL 8192               // 6272 doubles = 12544 floats
#define WS_MM   20736              // 2 doubles = 4 floats
#define WS_MBN  20744              // 16384 floats
#define WS_PB   40960              // 32*6272 floats
#define WS_PS   241664             // 32*6272
#define WS_PI   442368             // 32*6272 ints
#define WS_LIST 643072             // CAP ints
#define WS_RPV  644096             // CAP*64 doubles = 131072 floats (even offset: f64-aligned)
#define WS_RPI  775168             // CAP*64 ints

typedef __attribute__((ext_vector_type(8))) short bf16x8;
typedef __attribute__((ext_vector_type(4))) float f32x4;

// ---------------- threefry2x32-20, generalized key ----------------
__device__ __forceinline__ unsigned rotl32(unsigned v, int r){ return (v << r) | (v >> (32 - r)); }

__device__ __forceinline__ void tf2x32(unsigned k0, unsigned k1, unsigned x0, unsigned x1,
                                       unsigned& o0, unsigned& o1){
  const unsigned ks2 = k0 ^ k1 ^ 0x1BD11BDAu;
  x0 += k0; x1 += k1;
#define TF_ROUND(rot) { x0 += x1; x1 = rotl32(x1, rot); x1 ^= x0; }
  TF_ROUND(13) TF_ROUND(15) TF_ROUND(26) TF_ROUND(6)
  x0 += k1;  x1 += ks2 + 1u;
  TF_ROUND(17) TF_ROUND(29) TF_ROUND(16) TF_ROUND(24)
  x0 += ks2; x1 += k0 + 2u;
  TF_ROUND(13) TF_ROUND(15) TF_ROUND(26) TF_ROUND(6)
  x0 += k0;  x1 += k1 + 3u;
  TF_ROUND(17) TF_ROUND(29) TF_ROUND(16) TF_ROUND(24)
  x0 += k1;  x1 += ks2 + 4u;
  TF_ROUND(13) TF_ROUND(15) TF_ROUND(26) TF_ROUND(6)
  x0 += ks2; x1 += k0 + 5u;
#undef TF_ROUND
  o0 = x0; o1 = x1;
}

// JAX uniform-from-bits + XLA ErfInv32 (Giles), scaled by sqrt(2)
__device__ __forceinline__ float normal_from_bits(unsigned bits){
  unsigned fb = (bits >> 9) | 0x3F800000u;
  float f = __uint_as_float(fb) - 1.0f;
  const float lo = __uint_as_float(0xBF7FFFFFu);
  float u = fmaxf(lo, f * 2.0f + lo);
  float w = -log1pf(-u * u);
  float p;
  if (w < 5.0f){
    w = w - 2.5f;
    p = 2.81022636e-08f;
    p = fmaf(p, w, 3.43273939e-07f);
    p = fmaf(p, w, -3.5233877e-06f);
    p = fmaf(p, w, -4.39150654e-06f);
    p = fmaf(p, w, 0.00021858087f);
    p = fmaf(p, w, -0.00125372503f);
    p = fmaf(p, w, -0.00417768164f);
    p = fmaf(p, w, 0.246640727f);
    p = fmaf(p, w, 1.50140941f);
  } else {
    w = sqrtf(w) - 3.0f;
    p = -0.000200214257f;
    p = fmaf(p, w, 0.000100950558f);
    p = fmaf(p, w, 0.00134934322f);
    p = fmaf(p, w, -0.00367342844f);
    p = fmaf(p, w, 0.00573950773f);
    p = fmaf(p, w, -0.0076224613f);
    p = fmaf(p, w, 0.00943887047f);
    p = fmaf(p, w, 1.00167406f);
    p = fmaf(p, w, 2.83297682f);
  }
  return 1.41421356237f * (p * u);
}

// f32 -> bf16 with round-to-nearest-even (finite inputs)
__device__ __forceinline__ unsigned f2bf(float x){
  unsigned u = __float_as_uint(x);
  return (u + 0x7FFFu + ((u >> 16) & 1u)) >> 16;
}

// ---------------- kernel 0: ||m_j||^2 (exact f32) ----------------
__global__ __launch_bounds__(256) void mbnorm_kernel(const float* __restrict__ mb, float* __restrict__ mbn){
  int wid  = (blockIdx.x * 256 + threadIdx.x) >> 6;
  int lane = threadIdx.x & 63;
  if (wid >= N_BANK) return;
  const float* row = mb + (size_t)wid * K_DIM;
  float s = 0.f;
#pragma unroll
  for (int i = 0; i < 16; ++i){ float v = row[lane + i*64]; s = fmaf(v, v, s); }
#pragma unroll
  for (int off = 32; off; off >>= 1) s += __shfl_down(s, off);
  if (lane == 0) mbn[wid] = s;
}

// ---------------- init: zero the refine-list counter ----------------
__global__ void init_kernel(int* __restrict__ cnt){ if (threadIdx.x == 0) *cnt = 0; }

// ---------------- kernel A: bf16 MFMA GEMM, running top-2 min of s = ||m||^2 - 2 f.m ------
// 128x128 block tile, 4 waves (2x2), 64x64 per wave, mfma_f32_16x16x32_bf16.
// LDS fragment-major: elem[(chunk)*1024 + (k>>3)*128 + slot*8 + (k&7)], slot = (idx&15)^(chunk&3).
__global__ __launch_bounds__(256) void knn_min_kernel(
    const float* __restrict__ feat, const float* __restrict__ mb,
    const float* __restrict__ mbn,
    float* __restrict__ pbest, float* __restrict__ psec, int* __restrict__ pidx)
{
  __shared__ unsigned short As[8192];   // 128 rows x 64 k bf16
  __shared__ unsigned short Bs[8192];   // 128 cols x 64 k bf16

  const int t    = threadIdx.x;
  const int lane = t & 63;
  const int w    = t >> 6;             // wave 0..3
  const int wr   = w >> 1, wc = w & 1; // 2x2 wave grid
  const int lrow = lane >> 4;          // 0..3
  const int lcol = lane & 15;
  const int r0   = blockIdx.x * 128;
  const int j0base = blockIdx.y * JCHUNK;

  // A staging map: row = t&127, k-pair base = t>>7
  const int rA   = t & 127;
  const int kAp  = t >> 7;             // 0..1
  const int rowA = r0 + rA;
  const int bA   = rowA / HW;
  const int baseA = bA * CHW + (rowA - bA * HW);
  const int aChunk = rA >> 4;
  const int aSlot  = (rA & 15) ^ (aChunk & 3);
  // B staging map: k-pair = t&31, col base = t>>5
  const int pB = t & 31;
  const int cB = t >> 5;               // 0..7

  // per-lane top-2 state for 16 (mi,reg) rows
  float best[16], sec[16]; int bidx[16];
#pragma unroll
  for (int i = 0; i < 16; ++i){ best[i] = FLT_MAX; sec[i] = FLT_MAX; bidx[i] = 0; }

  for (int panel = 0; panel < JCHUNK/128; ++panel){
    const int j0 = j0base + panel*128;
    f32x4 acc[4][4];
#pragma unroll
    for (int mi = 0; mi < 4; ++mi)
#pragma unroll
      for (int ni = 0; ni < 4; ++ni) acc[mi][ni] = (f32x4){0.f,0.f,0.f,0.f};

    for (int k0 = 0; k0 < K_DIM; k0 += 64){
      __syncthreads();   // previous iteration's reads done before overwrite
      // stage A (f32 -> bf16 pairs packed as u32)
#pragma unroll
      for (int i = 0; i < 16; ++i){
        int p = kAp + 2*i;             // k-pair 0..31
        int k = 2*p;
        float x0 = feat[baseA + (k0 + k) * HW];
        float x1 = feat[baseA + (k0 + k + 1) * HW];
        unsigned u = f2bf(x0) | (f2bf(x1) << 16);
        ((unsigned*)As)[aChunk*512 + (k>>3)*64 + aSlot*4 + ((k&7)>>1)] = u;
      }
      // stage B
#pragma unroll
      for (int i = 0; i < 16; ++i){
        int col = cB + 8*i;
        int k = 2*pB;
        const float2 v = *reinterpret_cast<const float2*>(&mb[(size_t)(j0 + col) * K_DIM + k0 + k]);
        unsigned u = f2bf(v.x) | (f2bf(v.y) << 16);
        int bChunk = col >> 4;
        int bSlot  = (col & 15) ^ (bChunk & 3);
        ((unsigned*)Bs)[bChunk*512 + (k>>3)*64 + bSlot*4 + ((k&7)>>1)] = u;
      }
      __syncthreads();
      // 2 x (K=32) MFMA sub-steps
#pragma unroll
      for (int kk = 0; kk < 2; ++kk){
        bf16x8 av[4], bv[4];
#pragma unroll
        for (int mi = 0; mi < 4; ++mi){
          int ch = wr*4 + mi;
          av[mi] = *reinterpret_cast<const bf16x8*>(
            &As[ch*1024 + (kk*4 + lrow)*128 + ((lcol ^ (ch & 3)))*8]);
        }
#pragma unroll
        for (int ni = 0; ni < 4; ++ni){
          int ch = wc*4 + ni;
          bv[ni] = *reinterpret_cast<const bf16x8*>(
            &Bs[ch*1024 + (kk*4 + lrow)*128 + ((lcol ^ (ch & 3)))*8]);
        }
#pragma unroll
        for (int mi = 0; mi < 4; ++mi)
#pragma unroll
          for (int ni = 0; ni < 4; ++ni)
            acc[mi][ni] = __builtin_amdgcn_mfma_f32_16x16x32_bf16(av[mi], bv[ni], acc[mi][ni], 0, 0, 0);
      }
    }

    // fold this panel into per-lane top-2 (j ascending => strict < keeps lowest idx)
#pragma unroll
    for (int ni = 0; ni < 4; ++ni){
      int j = j0 + wc*64 + ni*16 + lcol;
      float mv = mbn[j];
#pragma unroll
      for (int mi = 0; mi < 4; ++mi)
#pragma unroll
        for (int rg = 0; rg < 4; ++rg){
          float s = fmaf(-2.0f, acc[mi][ni][rg], mv);
          int st = mi*4 + rg;
          if (s < best[st]){ sec[st] = best[st]; best[st] = s; bidx[st] = j; }
          else if (s < sec[st]){ sec[st] = s; }
        }
    }
  }

  // cross-lane top-2 merge within 16-lane groups (same lrow -> same rows)
#pragma unroll
  for (int st = 0; st < 16; ++st){
    float b = best[st], s2 = sec[st]; int ix = bidx[st];
#pragma unroll
    for (int m = 1; m < 16; m <<= 1){
      float ob = __shfl_xor(b, m);
      float os = __shfl_xor(s2, m);
      int   oi = __shfl_xor(ix, m);
      if (ob < b || (ob == b && oi < ix)){ s2 = fminf(os, b); b = ob; ix = oi; }
      else { s2 = fminf(s2, ob); }
    }
    best[st] = b; sec[st] = s2; bidx[st] = ix;
  }

  // cross-wave (wc) merge via LDS; rows differ by wr so only wc pairs collide
  __syncthreads();
  float* rb  = (float*)As;             // [128][2]
  float* rsv = rb + 256;
  int*   rix = (int*)(rsv + 256);
  if (lcol == 0){
#pragma unroll
    for (int st = 0; st < 16; ++st){
      int rloc = wr*64 + (st>>2)*16 + lrow*4 + (st&3);
      rb [rloc*2 + wc] = best[st];
      rsv[rloc*2 + wc] = sec[st];
      rix[rloc*2 + wc] = bidx[st];
    }
  }
  __syncthreads();
  if (t < 128){
    float b0 = rb[t*2], s0 = rsv[t*2]; int i0 = rix[t*2];
    float b1 = rb[t*2+1], s1 = rsv[t*2+1]; int i1 = rix[t*2+1];
    float gb, gs; int gi;
    if (b1 < b0 || (b1 == b0 && i1 < i0)){ gb = b1; gi = i1; gs = fminf(s1, b0); }
    else { gb = b0; gi = i0; gs = fminf(s0, b1); }
    pbest[blockIdx.y * M_ROWS + r0 + t] = gb;
    psec [blockIdx.y * M_ROWS + r0 + t] = gs;
    pidx [blockIdx.y * M_ROWS + r0 + t] = gi;
  }
}

// ---------------- kernel B: combine partials -> sidx + compact ambiguous list ----------
__global__ __launch_bounds__(256) void reduce_parts_kernel(
    const float* __restrict__ pbest, const float* __restrict__ psec, const int* __restrict__ pidx,
    int* __restrict__ sidx, int* __restrict__ list, int* __restrict__ cnt)
{
  int r = blockIdx.x * blockDim.x + threadIdx.x;
  if (r >= M_ROWS) return;
  float gb = FLT_MAX, gs = FLT_MAX; int gi = 0;
#pragma unroll
  for (int p = 0; p < JSPLIT; ++p){
    float v = pbest[p * M_ROWS + r], s2 = psec[p * M_ROWS + r]; int ii = pidx[p * M_ROWS + r];
    if (v < gb || (v == gb && ii < gi)){ gs = fminf(gb, s2); gb = v; gi = ii; }
    else { gs = fminf(gs, v); }
  }
  sidx[r] = gi;
  if (gs - gb < DELTA){
    int pos = atomicAdd(cnt, 1);
    if (pos < CAP) list[pos] = r;
  }
}

// ---------------- kernel C1: f64 partial re-scan (row, 256-bank-chunk) work items --------
__global__ __launch_bounds__(256) void refine_part_kernel(
    const float* __restrict__ feat, const float* __restrict__ mb,
    const int* __restrict__ list, const int* __restrict__ cnt,
    double* __restrict__ rpv, int* __restrict__ rpi)
{
  __shared__ float fs[K_DIM];
  __shared__ double wvv[4]; __shared__ int wvi[4];
  const int nf = min(*cnt, CAP);
  const int nwork = nf * 64;
  const int wv = threadIdx.x >> 6, lane = threadIdx.x & 63;

  for (int w = blockIdx.x; w < nwork; w += gridDim.x){
    const int fi = w >> 6, chunk = w & 63;
    const int r = list[fi];
    const int b = r / HW, hw = r - b * HW;
    for (int c = threadIdx.x; c < K_DIM; c += 256) fs[c] = feat[b * CHW + c * HW + hw];
    __syncthreads();

    double bv = DBL_MAX; int bi = N_BANK;
    for (int rr = 0; rr < 64; ++rr){
      int j = chunk * 256 + wv * 64 + rr;
      const float* mrow = mb + (size_t)j * K_DIM;
      double s = 0.0;
#pragma unroll
      for (int i = 0; i < 16; ++i){
        int c = lane + i * 64;
        double d = (double)fs[c] - (double)mrow[c];
        s = fma(d, d, s);
      }
#pragma unroll
      for (int off = 1; off < 64; off <<= 1) s += __shfl_xor(s, off);
      if (s < bv){ bv = s; bi = j; }
    }
    if (lane == 0){ wvv[wv] = bv; wvi[wv] = bi; }
    __syncthreads();
    if (threadIdx.x == 0){
      double gv = wvv[0]; int gi2 = wvi[0];
#pragma unroll
      for (int x = 1; x < 4; ++x){
        if (wvv[x] < gv || (wvv[x] == gv && wvi[x] < gi2)){ gv = wvv[x]; gi2 = wvi[x]; }
      }
      rpv[fi * 64 + chunk] = gv; rpi[fi * 64 + chunk] = gi2;
    }
    __syncthreads();
  }
}

// ---------------- kernel C2: combine 64 chunk-partials per refined row ----------------
__global__ __launch_bounds__(256) void refine_combine_kernel(
    const double* __restrict__ rpv, const int* __restrict__ rpi,
    const int* __restrict__ list, const int* __restrict__ cnt, int* __restrict__ sidx)
{
  const int nf = min(*cnt, CAP);
  const int wv = threadIdx.x >> 6, lane = threadIdx.x & 63;
  for (int fi = wv; fi < nf; fi += 4){
    double v = rpv[fi * 64 + lane]; int ii = rpi[fi * 64 + lane];
#pragma unroll
    for (int off = 1; off < 64; off <<= 1){
      double ov = __shfl_xor(v, off); int oi = __shfl_xor(ii, off);
      if (ov < v || (ov == v && oi < ii)){ v = ov; ii = oi; }
    }
    if (lane == 0) sidx[list[fi]] = ii;
  }
}

// ---------------- kernel D: f64 influence from the winner ----------------
__global__ __launch_bounds__(256) void influence_kernel(
    const float* __restrict__ feat, const float* __restrict__ mb,
    const int* __restrict__ sidx, double* __restrict__ infl)
{
  const int wid  = (blockIdx.x * 256 + threadIdx.x) >> 6;
  const int lane = threadIdx.x & 63;
  if (wid >= M_ROWS) return;
  const int r = wid;
  const int b = r / HW;
  const int baseR = b * CHW + (r - b * HW);
  const float* mrow = mb + (size_t)sidx[r] * K_DIM;
  double sabs = 0.0, sd2 = 0.0;
#pragma unroll
  for (int i = 0; i < 16; ++i){
    int c = lane + i*64;
    double d = (double)feat[baseR + c * HW] - (double)mrow[c];
    sd2  = fma(d, d, sd2);
    sabs += fabs(d);
  }
#pragma unroll
  for (int off = 1; off < 64; off <<= 1){
    sabs += __shfl_xor(sabs, off);
    sd2  += __shfl_xor(sd2, off);
  }
  if (lane == 0){
    double dist = sqrt(fmax(sd2, 0.0) + 1e-8);
    infl[r] = (sabs / 1024.0) / (dist + 1e-8);
  }
}

// ---------------- kernel E: f64 global min/max ----------------
__global__ __launch_bounds__(1024) void minmax_kernel(const double* __restrict__ infl, double* __restrict__ mm){
  __shared__ double smn[1024], smx[1024];
  int t = threadIdx.x;
  double mn = DBL_MAX, mx = -DBL_MAX;
  for (int i = t; i < M_ROWS; i += 1024){ double v = infl[i]; mn = fmin(mn, v); mx = fmax(mx, v); }
  smn[t] = mn; smx[t] = mx; __syncthreads();
  for (int off = 512; off > 0; off >>= 1){
    if (t < off){ smn[t] = fmin(smn[t], smn[t+off]); smx[t] = fmax(smx[t], smx[t+off]); }
    __syncthreads();
  }
  if (t == 0){ mm[0] = smn[0]; mm[1] = smx[0]; }
}

// ---------------- kernel F: f64 norm + std -> f32; stash mm into d_ws ----------------
__global__ __launch_bounds__(256) void normstd_kernel(
    const double* __restrict__ mm, const double* __restrict__ infl,
    float* __restrict__ norm_out, float* __restrict__ std_out, double* __restrict__ dws)
{
  int r = blockIdx.x * blockDim.x + threadIdx.x;
  if (r >= M_ROWS) return;
  double imin = mm[0], imax = mm[1];
  if (r == 0){ dws[0] = imin; dws[1] = imax; }
  double rng = imax - imin;
  double nrm = (rng > 1e-8) ? (infl[r] - imin) / rng : 0.0;
  norm_out[r] = (float)nrm;
  std_out[r]  = (float)(0.01 + nrm * 0.49);
}

// ---------------- kernel G: noise — partitionable (0,e), bits = o0 ^ o1 (VERIFIED r9) ------
__global__ __launch_bounds__(256) void noise_kernel(
    const float* __restrict__ feat, const float* __restrict__ stds, float* __restrict__ out)
{
  int tid = blockIdx.x * 256 + threadIdx.x;
  int b   = tid / CHW;
  int rem = tid - b * CHW;
  int c   = rem / HW;
  int hw  = rem - c * HW;
  int r   = b * HW + hw;
  unsigned e = (unsigned)r * (unsigned)K_DIM + (unsigned)c;
  unsigned o0, o1;
  tf2x32(0u, 1u, 0u, e, o0, o1);
  unsigned bits = o0 ^ o1;
  float n = normal_from_bits(bits);
  out[tid] = feat[tid] + n * stds[r];
}

// ---------------- diagnostics (inert when healthy) ----------------
__global__ void diag_kernel(const double* __restrict__ dws, float* __restrict__ out){
  double imin = dws[0], imax = dws[1];
  double rng = imax - imin;
  double code = 0.0, payload = 0.0;
  if (!(imin == imin) || !(imax == imax)){ code = 5e6; }
  else if (rng <= 1e-8){ code = 1e6; payload = fmin(fmax(rng, 0.0) * 1e12, 9e5); }
  else if (imax > 0.5){ code = 2e6; payload = fmin(imax * 1e4, 9e5); }
  else if (imin <= 1e-4){ code = 3e6; payload = fmin(fmax(imin, 0.0) * 1e6, 9e5); }
  else if (imax > 10.0 * imin){ code = 4e6; payload = fmin(imax * 1e4, 9e5); }
  if (code > 0.0) out[0] = (float)(code + payload);
}

__global__ void kat_kernel(float* __restrict__ out){
  float code = 0.f;
  unsigned a, b;
  tf2x32(0u, 0u, 0u, 0u, a, b);
  if (a != 0x6b200159u || b != 0x99ba4efeu) code = 1e10f;
  unsigned c2, d2;
  tf2x32(0x13198a2eu, 0x03707344u, 0x243f6a88u, 0x85a308d3u, c2, d2);
  if (code == 0.f && (c2 != 0xc4923a9cu || d2 != 0x483df7a0u)) code = 3e9f;
  float n = normal_from_bits(0x6b200159u);
  if (code == 0.f && fabsf(n - (-0.20584226f)) > 2e-5f) code = 1e9f;
  if (code > 0.f) out[0] = code;
}

extern "C" void kernel_launch(void* const* d_in, const int* in_sizes, int n_in,
                              void* d_out, int out_size, void* d_ws, size_t ws_size,
                              hipStream_t stream) {
  const float* feat = (const float*)d_in[0];
  const float* mb   = (const float*)d_in[1];
  float* out = (float*)d_out;

  int*    sidx = (int*)(out + WS_SIDX);
  double* infl = (double*)(out + WS_INFL);
  double* mm   = (double*)(out + WS_MM);
  float*  mbn  = out + WS_MBN;
  float*  pb   = out + WS_PB;
  float*  ps   = out + WS_PS;
  int*    pi   = (int*)(out + WS_PI);
  int*    list = (int*)(out + WS_LIST);
  double* rpv  = (double*)(out + WS_RPV);
  int*    rpi  = (int*)(out + WS_RPI);
  double* dws  = (double*)d_ws;
  int*    cnt  = (int*)((char*)d_ws + 16);
  float*  nrm  = out + OUT_NORM_OFF;
  float*  stds = out + OUT_STD_OFF;

  mbnorm_kernel<<<N_BANK/4, 256, 0, stream>>>(mb, mbn);
  init_kernel<<<1, 64, 0, stream>>>(cnt);
  knn_min_kernel<<<dim3(M_ROWS/128, JSPLIT), 256, 0, stream>>>(feat, mb, mbn, pb, ps, pi);
  reduce_parts_kernel<<<(M_ROWS + 255)/256, 256, 0, stream>>>(pb, ps, pi, sidx, list, cnt);
  refine_part_kernel<<<2048, 256, 0, stream>>>(feat, mb, list, cnt, rpv, rpi);
  refine_combine_kernel<<<1, 256, 0, stream>>>(rpv, rpi, list, cnt, sidx);
  influence_kernel<<<(M_ROWS*64)/256, 256, 0, stream>>>(feat, mb, sidx, infl);
  minmax_kernel<<<1, 1024, 0, stream>>>(infl, mm);
  normstd_kernel<<<(M_ROWS + 255)/256, 256, 0, stream>>>(mm, infl, nrm, stds, dws);
  noise_kernel<<<N_ELEMS/256, 256, 0, stream>>>(feat, stds, out);
  diag_kernel<<<1, 1, 0, stream>>>(dws, out);
  kat_kernel<<<1, 1, 0, stream>>>(out);
}

// Round 13
// 2111.915 us; speedup vs baseline: 2.5432x; 2.5432x over previous
//
#include <hip/hip_runtime.h>
#include <float.h>
#include <math.h>

// ---------------- problem constants ----------------
#define M_ROWS 6272        // 8*28*28 rows of f
#define N_BANK 16384
#define K_DIM  1024
#define HW     784         // 28*28
#define CHW    802816      // 1024*784 (per-batch stride in features)
#define OUT_NORM_OFF 6422528
#define OUT_STD_OFF  6428800
#define N_ELEMS 6422528    // 6272*1024

#define DELTA 0.5f         // bf16-scan ambiguity margin on s (deterministic-verified in r12)
#define JSPLIT 32
#define JCHUNK (N_BANK / JSPLIT)   // 512
#define CAP 1024           // max refined rows

// scratch layout (float offsets in d_out's noised region; all consumed before noise kernel)
#define WS_SIDX 0                  // 6272 ints
#define WS_INFL 8192               // 6272 doubles = 12544 floats
#define WS_MM   20736              // 2 doubles = 4 floats
#define WS_MBN  20744              // 16384 floats
#define WS_PB   40960              // 32*6272 floats
#define WS_PS   241664             // 32*6272
#define WS_PI   442368             // 32*6272 ints
#define WS_LIST 643072             // CAP ints
#define WS_RPV  644096             // CAP*64 doubles = 131072 floats (even offset: f64-aligned)
#define WS_RPI  775168             // CAP*64 ints

typedef __attribute__((ext_vector_type(8))) short bf16x8;
typedef __attribute__((ext_vector_type(4))) float f32x4;

// ---------------- threefry2x32-20, generalized key ----------------
__device__ __forceinline__ unsigned rotl32(unsigned v, int r){ return (v << r) | (v >> (32 - r)); }

__device__ __forceinline__ void tf2x32(unsigned k0, unsigned k1, unsigned x0, unsigned x1,
                                       unsigned& o0, unsigned& o1){
  const unsigned ks2 = k0 ^ k1 ^ 0x1BD11BDAu;
  x0 += k0; x1 += k1;
#define TF_ROUND(rot) { x0 += x1; x1 = rotl32(x1, rot); x1 ^= x0; }
  TF_ROUND(13) TF_ROUND(15) TF_ROUND(26) TF_ROUND(6)
  x0 += k1;  x1 += ks2 + 1u;
  TF_ROUND(17) TF_ROUND(29) TF_ROUND(16) TF_ROUND(24)
  x0 += ks2; x1 += k0 + 2u;
  TF_ROUND(13) TF_ROUND(15) TF_ROUND(26) TF_ROUND(6)
  x0 += k0;  x1 += k1 + 3u;
  TF_ROUND(17) TF_ROUND(29) TF_ROUND(16) TF_ROUND(24)
  x0 += k1;  x1 += ks2 + 4u;
  TF_ROUND(13) TF_ROUND(15) TF_ROUND(26) TF_ROUND(6)
  x0 += ks2; x1 += k0 + 5u;
#undef TF_ROUND
  o0 = x0; o1 = x1;
}

// JAX uniform-from-bits + XLA ErfInv32 (Giles), scaled by sqrt(2)
__device__ __forceinline__ float normal_from_bits(unsigned bits){
  unsigned fb = (bits >> 9) | 0x3F800000u;
  float f = __uint_as_float(fb) - 1.0f;
  const float lo = __uint_as_float(0xBF7FFFFFu);
  float u = fmaxf(lo, f * 2.0f + lo);
  float w = -log1pf(-u * u);
  float p;
  if (w < 5.0f){
    w = w - 2.5f;
    p = 2.81022636e-08f;
    p = fmaf(p, w, 3.43273939e-07f);
    p = fmaf(p, w, -3.5233877e-06f);
    p = fmaf(p, w, -4.39150654e-06f);
    p = fmaf(p, w, 0.00021858087f);
    p = fmaf(p, w, -0.00125372503f);
    p = fmaf(p, w, -0.00417768164f);
    p = fmaf(p, w, 0.246640727f);
    p = fmaf(p, w, 1.50140941f);
  } else {
    w = sqrtf(w) - 3.0f;
    p = -0.000200214257f;
    p = fmaf(p, w, 0.000100950558f);
    p = fmaf(p, w, 0.00134934322f);
    p = fmaf(p, w, -0.00367342844f);
    p = fmaf(p, w, 0.00573950773f);
    p = fmaf(p, w, -0.0076224613f);
    p = fmaf(p, w, 0.00943887047f);
    p = fmaf(p, w, 1.00167406f);
    p = fmaf(p, w, 2.83297682f);
  }
  return 1.41421356237f * (p * u);
}

// f32 -> bf16 round-to-nearest-even (finite inputs)
__device__ __forceinline__ unsigned f2bf(float x){
  unsigned u = __float_as_uint(x);
  return (u + 0x7FFFu + ((u >> 16) & 1u)) >> 16;
}

// ---------------- kernel 0: ||m_j||^2 (exact f32) ----------------
__global__ __launch_bounds__(256) void mbnorm_kernel(const float* __restrict__ mb, float* __restrict__ mbn){
  int wid  = (blockIdx.x * 256 + threadIdx.x) >> 6;
  int lane = threadIdx.x & 63;
  if (wid >= N_BANK) return;
  const float* row = mb + (size_t)wid * K_DIM;
  float s = 0.f;
#pragma unroll
  for (int i = 0; i < 16; ++i){ float v = row[lane + i*64]; s = fmaf(v, v, s); }
#pragma unroll
  for (int off = 32; off; off >>= 1) s += __shfl_down(s, off);
  if (lane == 0) mbn[wid] = s;
}

// ---------------- init: zero the refine-list counter ----------------
__global__ void init_kernel(int* __restrict__ cnt){ if (threadIdx.x == 0) *cnt = 0; }

// ---------------- kernel A: bf16 MFMA GEMM, running top-2 min of s = ||m||^2 - 2 f.m ------
// 128x128 block tile, 4 waves (2x2), 64x64 per wave, mfma_f32_16x16x32_bf16.
// LDS: row-major [idx][64] bf16, row stride 128 B, XOR swizzle: 16B-slot index = octet ^ (idx&7).
// Staging writes (uint4) and fragment reads (b128) are both bank-conflict-free by construction.
__global__ __launch_bounds__(256) void knn_min_kernel(
    const float* __restrict__ feat, const float* __restrict__ mb,
    const float* __restrict__ mbn,
    float* __restrict__ pbest, float* __restrict__ psec, int* __restrict__ pidx)
{
  __shared__ __align__(16) unsigned short As[8192];   // 128 rows x 64 k
  __shared__ __align__(16) unsigned short Bs[8192];   // 128 cols x 64 k

  const int t    = threadIdx.x;
  const int lane = t & 63;
  const int w    = t >> 6;
  const int wr   = w >> 1, wc = w & 1;
  const int lrow = lane >> 4;          // 0..3
  const int lcol = lane & 15;
  const int r0   = blockIdx.x * 128;
  const int j0base = blockIdx.y * JCHUNK;

  // staging map: thread owns row/col sIdx, k-octets {oBase, oBase+2, oBase+4, oBase+6}
  const int sIdx  = t & 127;
  const int oBase = t >> 7;            // 0..1
  const int rowA  = r0 + sIdx;
  const int bA    = rowA / HW;
  const int baseA = bA * CHW + (rowA - bA * HW);
  const int sSw   = sIdx & 7;          // swizzle key for this thread's stores

  // per-lane top-2 state for 16 (mi,reg) rows
  float best[16], sec[16]; int bidx[16];
#pragma unroll
  for (int i = 0; i < 16; ++i){ best[i] = FLT_MAX; sec[i] = FLT_MAX; bidx[i] = 0; }

  for (int panel = 0; panel < JCHUNK/128; ++panel){
    const int j0 = j0base + panel*128;
    f32x4 acc[4][4];
#pragma unroll
    for (int mi = 0; mi < 4; ++mi)
#pragma unroll
      for (int ni = 0; ni < 4; ++ni) acc[mi][ni] = (f32x4){0.f,0.f,0.f,0.f};

    for (int k0 = 0; k0 < K_DIM; k0 += 64){
      __syncthreads();   // previous iteration's reads complete before overwrite
      // stage A: 4 octets, 8 scalar f32 loads each (coalesced across rows), one uint4 store
#pragma unroll
      for (int ii = 0; ii < 4; ++ii){
        const int octet = oBase + 2*ii;
        const int kb = k0 + octet*8;
        float x0 = feat[baseA + (kb+0)*HW];
        float x1 = feat[baseA + (kb+1)*HW];
        float x2 = feat[baseA + (kb+2)*HW];
        float x3 = feat[baseA + (kb+3)*HW];
        float x4 = feat[baseA + (kb+4)*HW];
        float x5 = feat[baseA + (kb+5)*HW];
        float x6 = feat[baseA + (kb+6)*HW];
        float x7 = feat[baseA + (kb+7)*HW];
        uint4 q;
        q.x = f2bf(x0) | (f2bf(x1) << 16);
        q.y = f2bf(x2) | (f2bf(x3) << 16);
        q.z = f2bf(x4) | (f2bf(x5) << 16);
        q.w = f2bf(x6) | (f2bf(x7) << 16);
        ((uint4*)As)[sIdx*8 + (octet ^ sSw)] = q;
      }
      // stage B: 4 octets, 2 float4 loads each, one uint4 store
#pragma unroll
      for (int ii = 0; ii < 4; ++ii){
        const int octet = oBase + 2*ii;
        const float* src = mb + (size_t)(j0 + sIdx) * K_DIM + k0 + octet*8;
        const float4 v0 = *reinterpret_cast<const float4*>(src);
        const float4 v1 = *reinterpret_cast<const float4*>(src + 4);
        uint4 q;
        q.x = f2bf(v0.x) | (f2bf(v0.y) << 16);
        q.y = f2bf(v0.z) | (f2bf(v0.w) << 16);
        q.z = f2bf(v1.x) | (f2bf(v1.y) << 16);
        q.w = f2bf(v1.z) | (f2bf(v1.w) << 16);
        ((uint4*)Bs)[sIdx*8 + (octet ^ sSw)] = q;
      }
      __syncthreads();
      // 2 x (K=32) MFMA sub-steps; fragment: lane holds row=lcol(+16*ch), k = (kk*4+lrow)*8..+7
#pragma unroll
      for (int kk = 0; kk < 2; ++kk){
        const int oct = kk*4 + lrow;
        bf16x8 av[4], bv[4];
#pragma unroll
        for (int mi = 0; mi < 4; ++mi){
          int idx = (wr*4 + mi)*16 + lcol;
          av[mi] = *reinterpret_cast<const bf16x8*>(&As[idx*64 + ((oct ^ (lcol & 7)) << 3)]);
        }
#pragma unroll
        for (int ni = 0; ni < 4; ++ni){
          int idx = (wc*4 + ni)*16 + lcol;
          bv[ni] = *reinterpret_cast<const bf16x8*>(&Bs[idx*64 + ((oct ^ (lcol & 7)) << 3)]);
        }
#pragma unroll
        for (int mi = 0; mi < 4; ++mi)
#pragma unroll
          for (int ni = 0; ni < 4; ++ni)
            acc[mi][ni] = __builtin_amdgcn_mfma_f32_16x16x32_bf16(av[mi], bv[ni], acc[mi][ni], 0, 0, 0);
      }
    }

    // fold this panel into per-lane top-2 (j ascending => strict < keeps lowest idx)
#pragma unroll
    for (int ni = 0; ni < 4; ++ni){
      int j = j0 + wc*64 + ni*16 + lcol;
      float mv = mbn[j];
#pragma unroll
      for (int mi = 0; mi < 4; ++mi)
#pragma unroll
        for (int rg = 0; rg < 4; ++rg){
          float s = fmaf(-2.0f, acc[mi][ni][rg], mv);
          int st = mi*4 + rg;
          if (s < best[st]){ sec[st] = best[st]; best[st] = s; bidx[st] = j; }
          else if (s < sec[st]){ sec[st] = s; }
        }
    }
  }

  // cross-lane top-2 merge within 16-lane groups (same lrow -> same rows)
#pragma unroll
  for (int st = 0; st < 16; ++st){
    float b = best[st], s2 = sec[st]; int ix = bidx[st];
#pragma unroll
    for (int m = 1; m < 16; m <<= 1){
      float ob = __shfl_xor(b, m);
      float os = __shfl_xor(s2, m);
      int   oi = __shfl_xor(ix, m);
      if (ob < b || (ob == b && oi < ix)){ s2 = fminf(os, b); b = ob; ix = oi; }
      else { s2 = fminf(s2, ob); }
    }
    best[st] = b; sec[st] = s2; bidx[st] = ix;
  }

  // cross-wave (wc) merge via LDS
  __syncthreads();
  float* rb  = (float*)As;             // [128][2]
  float* rsv = rb + 256;
  int*   rix = (int*)(rsv + 256);
  if (lcol == 0){
#pragma unroll
    for (int st = 0; st < 16; ++st){
      int rloc = wr*64 + (st>>2)*16 + lrow*4 + (st&3);
      rb [rloc*2 + wc] = best[st];
      rsv[rloc*2 + wc] = sec[st];
      rix[rloc*2 + wc] = bidx[st];
    }
  }
  __syncthreads();
  if (t < 128){
    float b0 = rb[t*2], s0 = rsv[t*2]; int i0 = rix[t*2];
    float b1 = rb[t*2+1], s1 = rsv[t*2+1]; int i1 = rix[t*2+1];
    float gb, gs; int gi;
    if (b1 < b0 || (b1 == b0 && i1 < i0)){ gb = b1; gi = i1; gs = fminf(s1, b0); }
    else { gb = b0; gi = i0; gs = fminf(s0, b1); }
    pbest[blockIdx.y * M_ROWS + r0 + t] = gb;
    psec [blockIdx.y * M_ROWS + r0 + t] = gs;
    pidx [blockIdx.y * M_ROWS + r0 + t] = gi;
  }
}

// ---------------- kernel B: combine partials -> sidx + compact ambiguous list ----------
__global__ __launch_bounds__(256) void reduce_parts_kernel(
    const float* __restrict__ pbest, const float* __restrict__ psec, const int* __restrict__ pidx,
    int* __restrict__ sidx, int* __restrict__ list, int* __restrict__ cnt)
{
  int r = blockIdx.x * blockDim.x + threadIdx.x;
  if (r >= M_ROWS) return;
  float gb = FLT_MAX, gs = FLT_MAX; int gi = 0;
#pragma unroll
  for (int p = 0; p < JSPLIT; ++p){
    float v = pbest[p * M_ROWS + r], s2 = psec[p * M_ROWS + r]; int ii = pidx[p * M_ROWS + r];
    if (v < gb || (v == gb && ii < gi)){ gs = fminf(gb, s2); gb = v; gi = ii; }
    else { gs = fminf(gs, v); }
  }
  sidx[r] = gi;
  if (gs - gb < DELTA){
    int pos = atomicAdd(cnt, 1);
    if (pos < CAP) list[pos] = r;
  }
}

// ---------------- kernel C1: f64 partial re-scan (row, 256-bank-chunk) work items --------
__global__ __launch_bounds__(256) void refine_part_kernel(
    const float* __restrict__ feat, const float* __restrict__ mb,
    const int* __restrict__ list, const int* __restrict__ cnt,
    double* __restrict__ rpv, int* __restrict__ rpi)
{
  __shared__ float fs[K_DIM];
  __shared__ double wvv[4]; __shared__ int wvi[4];
  const int nf = min(*cnt, CAP);
  const int nwork = nf * 64;
  const int wv = threadIdx.x >> 6, lane = threadIdx.x & 63;

  for (int w = blockIdx.x; w < nwork; w += gridDim.x){
    const int fi = w >> 6, chunk = w & 63;
    const int r = list[fi];
    const int b = r / HW, hw = r - b * HW;
    for (int c = threadIdx.x; c < K_DIM; c += 256) fs[c] = feat[b * CHW + c * HW + hw];
    __syncthreads();

    double bv = DBL_MAX; int bi = N_BANK;
    for (int rr = 0; rr < 64; ++rr){
      int j = chunk * 256 + wv * 64 + rr;
      const float* mrow = mb + (size_t)j * K_DIM;
      double s = 0.0;
#pragma unroll
      for (int i = 0; i < 16; ++i){
        int c = lane + i * 64;
        double d = (double)fs[c] - (double)mrow[c];
        s = fma(d, d, s);
      }
#pragma unroll
      for (int off = 1; off < 64; off <<= 1) s += __shfl_xor(s, off);
      if (s < bv){ bv = s; bi = j; }
    }
    if (lane == 0){ wvv[wv] = bv; wvi[wv] = bi; }
    __syncthreads();
    if (threadIdx.x == 0){
      double gv = wvv[0]; int gi2 = wvi[0];
#pragma unroll
      for (int x = 1; x < 4; ++x){
        if (wvv[x] < gv || (wvv[x] == gv && wvi[x] < gi2)){ gv = wvv[x]; gi2 = wvi[x]; }
      }
      rpv[fi * 64 + chunk] = gv; rpi[fi * 64 + chunk] = gi2;
    }
    __syncthreads();
  }
}

// ---------------- kernel C2: combine 64 chunk-partials per refined row ----------------
__global__ __launch_bounds__(256) void refine_combine_kernel(
    const double* __restrict__ rpv, const int* __restrict__ rpi,
    const int* __restrict__ list, const int* __restrict__ cnt, int* __restrict__ sidx)
{
  const int nf = min(*cnt, CAP);
  const int wv = threadIdx.x >> 6, lane = threadIdx.x & 63;
  for (int fi = wv; fi < nf; fi += 4){
    double v = rpv[fi * 64 + lane]; int ii = rpi[fi * 64 + lane];
#pragma unroll
    for (int off = 1; off < 64; off <<= 1){
      double ov = __shfl_xor(v, off); int oi = __shfl_xor(ii, off);
      if (ov < v || (ov == v && oi < ii)){ v = ov; ii = oi; }
    }
    if (lane == 0) sidx[list[fi]] = ii;
  }
}

// ---------------- kernel D: f64 influence from the winner ----------------
__global__ __launch_bounds__(256) void influence_kernel(
    const float* __restrict__ feat, const float* __restrict__ mb,
    const int* __restrict__ sidx, double* __restrict__ infl)
{
  const int wid  = (blockIdx.x * 256 + threadIdx.x) >> 6;
  const int lane = threadIdx.x & 63;
  if (wid >= M_ROWS) return;
  const int r = wid;
  const int b = r / HW;
  const int baseR = b * CHW + (r - b * HW);
  const float* mrow = mb + (size_t)sidx[r] * K_DIM;
  double sabs = 0.0, sd2 = 0.0;
#pragma unroll
  for (int i = 0; i < 16; ++i){
    int c = lane + i*64;
    double d = (double)feat[baseR + c * HW] - (double)mrow[c];
    sd2  = fma(d, d, sd2);
    sabs += fabs(d);
  }
#pragma unroll
  for (int off = 1; off < 64; off <<= 1){
    sabs += __shfl_xor(sabs, off);
    sd2  += __shfl_xor(sd2, off);
  }
  if (lane == 0){
    double dist = sqrt(fmax(sd2, 0.0) + 1e-8);
    infl[r] = (sabs / 1024.0) / (dist + 1e-8);
  }
}

// ---------------- kernel E: f64 global min/max ----------------
__global__ __launch_bounds__(1024) void minmax_kernel(const double* __restrict__ infl, double* __restrict__ mm){
  __shared__ double smn[1024], smx[1024];
  int t = threadIdx.x;
  double mn = DBL_MAX, mx = -DBL_MAX;
  for (int i = t; i < M_ROWS; i += 1024){ double v = infl[i]; mn = fmin(mn, v); mx = fmax(mx, v); }
  smn[t] = mn; smx[t] = mx; __syncthreads();
  for (int off = 512; off > 0; off >>= 1){
    if (t < off){ smn[t] = fmin(smn[t], smn[t+off]); smx[t] = fmax(smx[t], smx[t+off]); }
    __syncthreads();
  }
  if (t == 0){ mm[0] = smn[0]; mm[1] = smx[0]; }
}

// ---------------- kernel F: f64 norm + std -> f32; stash mm into d_ws ----------------
__global__ __launch_bounds__(256) void normstd_kernel(
    const double* __restrict__ mm, const double* __restrict__ infl,
    float* __restrict__ norm_out, float* __restrict__ std_out, double* __restrict__ dws)
{
  int r = blockIdx.x * blockDim.x + threadIdx.x;
  if (r >= M_ROWS) return;
  double imin = mm[0], imax = mm[1];
  if (r == 0){ dws[0] = imin; dws[1] = imax; }
  double rng = imax - imin;
  double nrm = (rng > 1e-8) ? (infl[r] - imin) / rng : 0.0;
  norm_out[r] = (float)nrm;
  std_out[r]  = (float)(0.01 + nrm * 0.49);
}

// ---------------- kernel G: noise — partitionable (0,e), bits = o0 ^ o1 (VERIFIED r9) ------
__global__ __launch_bounds__(256) void noise_kernel(
    const float* __restrict__ feat, const float* __restrict__ stds, float* __restrict__ out)
{
  int tid = blockIdx.x * 256 + threadIdx.x;
  int b   = tid / CHW;
  int rem = tid - b * CHW;
  int c   = rem / HW;
  int hw  = rem - c * HW;
  int r   = b * HW + hw;
  unsigned e = (unsigned)r * (unsigned)K_DIM + (unsigned)c;
  unsigned o0, o1;
  tf2x32(0u, 1u, 0u, e, o0, o1);
  unsigned bits = o0 ^ o1;
  float n = normal_from_bits(bits);
  out[tid] = feat[tid] + n * stds[r];
}

// ---------------- diagnostics (inert when healthy) ----------------
__global__ void diag_kernel(const double* __restrict__ dws, float* __restrict__ out){
  double imin = dws[0], imax = dws[1];
  double rng = imax - imin;
  double code = 0.0, payload = 0.0;
  if (!(imin == imin) || !(imax == imax)){ code = 5e6; }
  else if (rng <= 1e-8){ code = 1e6; payload = fmin(fmax(rng, 0.0) * 1e12, 9e5); }
  else if (imax > 0.5){ code = 2e6; payload = fmin(imax * 1e4, 9e5); }
  else if (imin <= 1e-4){ code = 3e6; payload = fmin(fmax(imin, 0.0) * 1e6, 9e5); }
  else if (imax > 10.0 * imin){ code = 4e6; payload = fmin(imax * 1e4, 9e5); }
  if (code > 0.0) out[0] = (float)(code + payload);
}

__global__ void kat_kernel(float* __restrict__ out){
  float code = 0.f;
  unsigned a, b;
  tf2x32(0u, 0u, 0u, 0u, a, b);
  if (a != 0x6b200159u || b != 0x99ba4efeu) code = 1e10f;
  unsigned c2, d2;
  tf2x32(0x13198a2eu, 0x03707344u, 0x243f6a88u, 0x85a308d3u, c2, d2);
  if (code == 0.f && (c2 != 0xc4923a9cu || d2 != 0x483df7a0u)) code = 3e9f;
  float n = normal_from_bits(0x6b200159u);
  if (code == 0.f && fabsf(n - (-0.20584226f)) > 2e-5f) code = 1e9f;
  if (code > 0.f) out[0] = code;
}

extern "C" void kernel_launch(void* const* d_in, const int* in_sizes, int n_in,
                              void* d_out, int out_size, void* d_ws, size_t ws_size,
                              hipStream_t stream) {
  const float* feat = (const float*)d_in[0];
  const float* mb   = (const float*)d_in[1];
  float* out = (float*)d_out;

  int*    sidx = (int*)(out + WS_SIDX);
  double* infl = (double*)(out + WS_INFL);
  double* mm   = (double*)(out + WS_MM);
  float*  mbn  = out + WS_MBN;
  float*  pb   = out + WS_PB;
  float*  ps   = out + WS_PS;
  int*    pi   = (int*)(out + WS_PI);
  int*    list = (int*)(out + WS_LIST);
  double* rpv  = (double*)(out + WS_RPV);
  int*    rpi  = (int*)(out + WS_RPI);
  double* dws  = (double*)d_ws;
  int*    cnt  = (int*)((char*)d_ws + 16);
  float*  nrm  = out + OUT_NORM_OFF;
  float*  stds = out + OUT_STD_OFF;

  mbnorm_kernel<<<N_BANK/4, 256, 0, stream>>>(mb, mbn);
  init_kernel<<<1, 64, 0, stream>>>(cnt);
  knn_min_kernel<<<dim3(M_ROWS/128, JSPLIT), 256, 0, stream>>>(feat, mb, mbn, pb, ps, pi);
  reduce_parts_kernel<<<(M_ROWS + 255)/256, 256, 0, stream>>>(pb, ps, pi, sidx, list, cnt);
  refine_part_kernel<<<2048, 256, 0, stream>>>(feat, mb, list, cnt, rpv, rpi);
  refine_combine_kernel<<<1, 256, 0, stream>>>(rpv, rpi, list, cnt, sidx);
  influence_kernel<<<(M_ROWS*64)/256, 256, 0, stream>>>(feat, mb, sidx, infl);
  minmax_kernel<<<1, 1024, 0, stream>>>(infl, mm);
  normstd_kernel<<<(M_ROWS + 255)/256, 256, 0, stream>>>(mm, infl, nrm, stds, dws);
  noise_kernel<<<N_ELEMS/256, 256, 0, stream>>>(feat, stds, out);
  diag_kernel<<<1, 1, 0, stream>>>(dws, out);
  kat_kernel<<<1, 1, 0, stream>>>(out);
}

// Round 14
// 1878.731 us; speedup vs baseline: 2.8589x; 1.1241x over previous
//
#include <hip/hip_runtime.h>
#include <float.h>
#include <math.h>

// ---------------- problem constants ----------------
#define M_ROWS 6272        // 8*28*28 rows of f
#define N_BANK 16384
#define K_DIM  1024
#define HW     784         // 28*28
#define CHW    802816      // 1024*784 (per-batch stride in features)
#define OUT_NORM_OFF 6422528
#define OUT_STD_OFF  6428800
#define N_ELEMS 6422528    // 6272*1024

#define DELTA 0.5f         // bf16-scan ambiguity margin on s (deterministic-verified r12/r13)
#define JSPLIT 32
#define JCHUNK (N_BANK / JSPLIT)   // 512
#define CAP 1024           // max refined rows

// scratch layout (float offsets in d_out's noised region; all consumed before noise kernel)
#define WS_SIDX 0                  // 6272 ints
#define WS_INFL 8192               // 6272 doubles = 12544 floats
#define WS_MM   20736              // 2 doubles = 4 floats
#define WS_MBN  20744              // 16384 floats
#define WS_PB   40960              // 32*6272 floats
#define WS_PS   241664             // 32*6272
#define WS_PI   442368             // 32*6272 ints
#define WS_LIST 643072             // CAP ints
#define WS_RPV  644096             // CAP*64 doubles = 131072 floats (f64-aligned)
#define WS_RPI  775168             // CAP*64 ints -> ends 840704
#define WS_FBF  1048576            // 6272*1024 bf16 = 3211264 floats -> ends 4259840 (< 6422528)

typedef __attribute__((ext_vector_type(8))) short bf16x8;
typedef __attribute__((ext_vector_type(4))) float f32x4;

// ---------------- threefry2x32-20, generalized key ----------------
__device__ __forceinline__ unsigned rotl32(unsigned v, int r){ return (v << r) | (v >> (32 - r)); }

__device__ __forceinline__ void tf2x32(unsigned k0, unsigned k1, unsigned x0, unsigned x1,
                                       unsigned& o0, unsigned& o1){
  const unsigned ks2 = k0 ^ k1 ^ 0x1BD11BDAu;
  x0 += k0; x1 += k1;
#define TF_ROUND(rot) { x0 += x1; x1 = rotl32(x1, rot); x1 ^= x0; }
  TF_ROUND(13) TF_ROUND(15) TF_ROUND(26) TF_ROUND(6)
  x0 += k1;  x1 += ks2 + 1u;
  TF_ROUND(17) TF_ROUND(29) TF_ROUND(16) TF_ROUND(24)
  x0 += ks2; x1 += k0 + 2u;
  TF_ROUND(13) TF_ROUND(15) TF_ROUND(26) TF_ROUND(6)
  x0 += k0;  x1 += k1 + 3u;
  TF_ROUND(17) TF_ROUND(29) TF_ROUND(16) TF_ROUND(24)
  x0 += k1;  x1 += ks2 + 4u;
  TF_ROUND(13) TF_ROUND(15) TF_ROUND(26) TF_ROUND(6)
  x0 += ks2; x1 += k0 + 5u;
#undef TF_ROUND
  o0 = x0; o1 = x1;
}

// JAX uniform-from-bits + XLA ErfInv32 (Giles), scaled by sqrt(2)
__device__ __forceinline__ float normal_from_bits(unsigned bits){
  unsigned fb = (bits >> 9) | 0x3F800000u;
  float f = __uint_as_float(fb) - 1.0f;
  const float lo = __uint_as_float(0xBF7FFFFFu);
  float u = fmaxf(lo, f * 2.0f + lo);
  float w = -log1pf(-u * u);
  float p;
  if (w < 5.0f){
    w = w - 2.5f;
    p = 2.81022636e-08f;
    p = fmaf(p, w, 3.43273939e-07f);
    p = fmaf(p, w, -3.5233877e-06f);
    p = fmaf(p, w, -4.39150654e-06f);
    p = fmaf(p, w, 0.00021858087f);
    p = fmaf(p, w, -0.00125372503f);
    p = fmaf(p, w, -0.00417768164f);
    p = fmaf(p, w, 0.246640727f);
    p = fmaf(p, w, 1.50140941f);
  } else {
    w = sqrtf(w) - 3.0f;
    p = -0.000200214257f;
    p = fmaf(p, w, 0.000100950558f);
    p = fmaf(p, w, 0.00134934322f);
    p = fmaf(p, w, -0.00367342844f);
    p = fmaf(p, w, 0.00573950773f);
    p = fmaf(p, w, -0.0076224613f);
    p = fmaf(p, w, 0.00943887047f);
    p = fmaf(p, w, 1.00167406f);
    p = fmaf(p, w, 2.83297682f);
  }
  return 1.41421356237f * (p * u);
}

// f32 -> bf16 round-to-nearest-even (finite inputs)
__device__ __forceinline__ unsigned f2bf(float x){
  unsigned u = __float_as_uint(x);
  return (u + 0x7FFFu + ((u >> 16) & 1u)) >> 16;
}

// ---------------- kernel 0: ||m_j||^2 (exact f32) ----------------
__global__ __launch_bounds__(256) void mbnorm_kernel(const float* __restrict__ mb, float* __restrict__ mbn){
  int wid  = (blockIdx.x * 256 + threadIdx.x) >> 6;
  int lane = threadIdx.x & 63;
  if (wid >= N_BANK) return;
  const float* row = mb + (size_t)wid * K_DIM;
  float s = 0.f;
#pragma unroll
  for (int i = 0; i < 16; ++i){ float v = row[lane + i*64]; s = fmaf(v, v, s); }
#pragma unroll
  for (int off = 32; off; off >>= 1) s += __shfl_down(s, off);
  if (lane == 0) mbn[wid] = s;
}

// ---------------- init: zero the refine-list counter ----------------
__global__ void init_kernel(int* __restrict__ cnt){ if (threadIdx.x == 0) *cnt = 0; }

// ---------------- kernel P: feat (BCHW f32) -> fbf [r][c] bf16, LDS-transposed ----------
// tile: 16 hw x 128 c per block; grid (49, 8, 8) = (hwTile, cTile, b)
__global__ __launch_bounds__(256) void featbf_kernel(const float* __restrict__ feat,
                                                     unsigned short* __restrict__ fbf){
  __shared__ unsigned short tile[128][18];   // [c][hw], stride 9 words: gcd(9,32)=1
  const int b   = blockIdx.z;
  const int hw0 = blockIdx.x * 16;
  const int c0  = blockIdx.y * 128;
  const int t   = threadIdx.x;
  const int hw_l = t & 15, c_l = t >> 4;     // read map: lanes -> hw (coalesced 64B)
#pragma unroll
  for (int i = 0; i < 8; ++i){
    int c = c_l + 16*i;
    float v = feat[b*CHW + (c0 + c)*HW + hw0 + hw_l];
    tile[c][hw_l] = (unsigned short)f2bf(v);
  }
  __syncthreads();
  const int c_w = t & 127, hw_b = t >> 7;    // write map: lanes -> c (coalesced 128B)
#pragma unroll
  for (int i = 0; i < 8; ++i){
    int hw_w = hw_b + 2*i;
    fbf[(size_t)(b*HW + hw0 + hw_w)*K_DIM + c0 + c_w] = tile[c_w][hw_w];
  }
}

// ---------------- kernel A: bf16 MFMA GEMM with 2-phase register prefetch ----------------
// 128x128 tile, 4 waves (2x2), 64x64/wave, mfma_f32_16x16x32_bf16, BK=64.
// LDS row-major [idx][64k] bf16 with XOR swizzle slot = octet ^ (idx&7) (r13-verified, 0 conflicts).
// A staged raw from fbf (no conversion); B staged from mb with f2bf. Numerics identical to r13.
__global__ __launch_bounds__(256) void knn_min_kernel(
    const unsigned short* __restrict__ fbf, const float* __restrict__ mb,
    const float* __restrict__ mbn,
    float* __restrict__ pbest, float* __restrict__ psec, int* __restrict__ pidx)
{
  __shared__ __align__(16) unsigned short As[8192];   // 128 rows x 64 k
  __shared__ __align__(16) unsigned short Bs[8192];   // 128 cols x 64 k

  const int t    = threadIdx.x;
  const int lane = t & 63;
  const int w    = t >> 6;
  const int wr   = w >> 1, wc = w & 1;
  const int lrow = lane >> 4;
  const int lcol = lane & 15;
  const int r0   = blockIdx.x * 128;
  const int j0base = blockIdx.y * JCHUNK;

  // item map (shared by A and B staging): id = t + 256*ii -> idx = id>>3 (0..127), oct = id&7
  uint4  ra[4];
  float4 rb0[4], rb1[4];

  float best[16], sec[16]; int bidx[16];
#pragma unroll
  for (int i = 0; i < 16; ++i){ best[i] = FLT_MAX; sec[i] = FLT_MAX; bidx[i] = 0; }

  f32x4 acc[4][4];

  // prefetch step 0
#pragma unroll
  for (int ii = 0; ii < 4; ++ii){
    int id = t + 256*ii; int idx = id >> 3, oct = id & 7;
    ra[ii] = *reinterpret_cast<const uint4*>(&fbf[(size_t)(r0 + idx)*K_DIM + oct*8]);
    const float* src = mb + (size_t)(j0base + idx)*K_DIM + oct*8;
    rb0[ii] = *reinterpret_cast<const float4*>(src);
    rb1[ii] = *reinterpret_cast<const float4*>(src + 4);
  }

  for (int s = 0; s < 64; ++s){
    const int panel = s >> 4;
    const int kstep = s & 15;
    if (kstep == 0){
#pragma unroll
      for (int mi = 0; mi < 4; ++mi)
#pragma unroll
        for (int ni = 0; ni < 4; ++ni) acc[mi][ni] = (f32x4){0.f,0.f,0.f,0.f};
    }
    __syncthreads();   // previous MFMA reads complete before overwrite
    // write prefetched regs -> LDS
#pragma unroll
    for (int ii = 0; ii < 4; ++ii){
      int id = t + 256*ii; int idx = id >> 3, oct = id & 7;
      ((uint4*)As)[idx*8 + (oct ^ (idx & 7))] = ra[ii];
      uint4 q;
      q.x = f2bf(rb0[ii].x) | (f2bf(rb0[ii].y) << 16);
      q.y = f2bf(rb0[ii].z) | (f2bf(rb0[ii].w) << 16);
      q.z = f2bf(rb1[ii].x) | (f2bf(rb1[ii].y) << 16);
      q.w = f2bf(rb1[ii].z) | (f2bf(rb1[ii].w) << 16);
      ((uint4*)Bs)[idx*8 + (oct ^ (idx & 7))] = q;
    }
    __syncthreads();
    // issue next step's global loads (latency hides under MFMA below)
    if (s < 63){
      const int s2 = s + 1;
      const int k0n = (s2 & 15) * 64;
      const int j0n = j0base + (s2 >> 4) * 128;
#pragma unroll
      for (int ii = 0; ii < 4; ++ii){
        int id = t + 256*ii; int idx = id >> 3, oct = id & 7;
        ra[ii] = *reinterpret_cast<const uint4*>(&fbf[(size_t)(r0 + idx)*K_DIM + k0n + oct*8]);
        const float* src = mb + (size_t)(j0n + idx)*K_DIM + k0n + oct*8;
        rb0[ii] = *reinterpret_cast<const float4*>(src);
        rb1[ii] = *reinterpret_cast<const float4*>(src + 4);
      }
    }
    // 2 x (K=32) MFMA sub-steps from LDS
#pragma unroll
    for (int kk = 0; kk < 2; ++kk){
      const int oct = kk*4 + lrow;
      bf16x8 av[4], bv[4];
#pragma unroll
      for (int mi = 0; mi < 4; ++mi){
        int idx = (wr*4 + mi)*16 + lcol;
        av[mi] = *reinterpret_cast<const bf16x8*>(&As[idx*64 + ((oct ^ (lcol & 7)) << 3)]);
      }
#pragma unroll
      for (int ni = 0; ni < 4; ++ni){
        int idx = (wc*4 + ni)*16 + lcol;
        bv[ni] = *reinterpret_cast<const bf16x8*>(&Bs[idx*64 + ((oct ^ (lcol & 7)) << 3)]);
      }
#pragma unroll
      for (int mi = 0; mi < 4; ++mi)
#pragma unroll
        for (int ni = 0; ni < 4; ++ni)
          acc[mi][ni] = __builtin_amdgcn_mfma_f32_16x16x32_bf16(av[mi], bv[ni], acc[mi][ni], 0, 0, 0);
    }
    // fold panel into per-lane top-2 at panel end (register-only)
    if (kstep == 15){
      const int j0 = j0base + panel*128;
#pragma unroll
      for (int ni = 0; ni < 4; ++ni){
        int j = j0 + wc*64 + ni*16 + lcol;
        float mv = mbn[j];
#pragma unroll
        for (int mi = 0; mi < 4; ++mi)
#pragma unroll
          for (int rg = 0; rg < 4; ++rg){
            float sv = fmaf(-2.0f, acc[mi][ni][rg], mv);
            int st = mi*4 + rg;
            if (sv < best[st]){ sec[st] = best[st]; best[st] = sv; bidx[st] = j; }
            else if (sv < sec[st]){ sec[st] = sv; }
          }
      }
    }
  }

  // cross-lane top-2 merge within 16-lane groups
#pragma unroll
  for (int st = 0; st < 16; ++st){
    float b = best[st], s2 = sec[st]; int ix = bidx[st];
#pragma unroll
    for (int m = 1; m < 16; m <<= 1){
      float ob = __shfl_xor(b, m);
      float os = __shfl_xor(s2, m);
      int   oi = __shfl_xor(ix, m);
      if (ob < b || (ob == b && oi < ix)){ s2 = fminf(os, b); b = ob; ix = oi; }
      else { s2 = fminf(s2, ob); }
    }
    best[st] = b; sec[st] = s2; bidx[st] = ix;
  }

  // cross-wave (wc) merge via LDS
  __syncthreads();
  float* rb  = (float*)As;             // [128][2]
  float* rsv = rb + 256;
  int*   rix = (int*)(rsv + 256);
  if (lcol == 0){
#pragma unroll
    for (int st = 0; st < 16; ++st){
      int rloc = wr*64 + (st>>2)*16 + lrow*4 + (st&3);
      rb [rloc*2 + wc] = best[st];
      rsv[rloc*2 + wc] = sec[st];
      rix[rloc*2 + wc] = bidx[st];
    }
  }
  __syncthreads();
  if (t < 128){
    float b0 = rb[t*2], s0 = rsv[t*2]; int i0 = rix[t*2];
    float b1 = rb[t*2+1], s1 = rsv[t*2+1]; int i1 = rix[t*2+1];
    float gb, gs; int gi;
    if (b1 < b0 || (b1 == b0 && i1 < i0)){ gb = b1; gi = i1; gs = fminf(s1, b0); }
    else { gb = b0; gi = i0; gs = fminf(s0, b1); }
    pbest[blockIdx.y * M_ROWS + r0 + t] = gb;
    psec [blockIdx.y * M_ROWS + r0 + t] = gs;
    pidx [blockIdx.y * M_ROWS + r0 + t] = gi;
  }
}

// ---------------- kernel B: combine partials -> sidx + compact ambiguous list ----------
__global__ __launch_bounds__(256) void reduce_parts_kernel(
    const float* __restrict__ pbest, const float* __restrict__ psec, const int* __restrict__ pidx,
    int* __restrict__ sidx, int* __restrict__ list, int* __restrict__ cnt)
{
  int r = blockIdx.x * blockDim.x + threadIdx.x;
  if (r >= M_ROWS) return;
  float gb = FLT_MAX, gs = FLT_MAX; int gi = 0;
#pragma unroll
  for (int p = 0; p < JSPLIT; ++p){
    float v = pbest[p * M_ROWS + r], s2 = psec[p * M_ROWS + r]; int ii = pidx[p * M_ROWS + r];
    if (v < gb || (v == gb && ii < gi)){ gs = fminf(gb, s2); gb = v; gi = ii; }
    else { gs = fminf(gs, v); }
  }
  sidx[r] = gi;
  if (gs - gb < DELTA){
    int pos = atomicAdd(cnt, 1);
    if (pos < CAP) list[pos] = r;
  }
}

// ---------------- kernel C1: f64 partial re-scan (row, 256-bank-chunk) work items --------
__global__ __launch_bounds__(256) void refine_part_kernel(
    const float* __restrict__ feat, const float* __restrict__ mb,
    const int* __restrict__ list, const int* __restrict__ cnt,
    double* __restrict__ rpv, int* __restrict__ rpi)
{
  __shared__ float fs[K_DIM];
  __shared__ double wvv[4]; __shared__ int wvi[4];
  const int nf = min(*cnt, CAP);
  const int nwork = nf * 64;
  const int wv = threadIdx.x >> 6, lane = threadIdx.x & 63;

  for (int w = blockIdx.x; w < nwork; w += gridDim.x){
    const int fi = w >> 6, chunk = w & 63;
    const int r = list[fi];
    const int b = r / HW, hw = r - b * HW;
    for (int c = threadIdx.x; c < K_DIM; c += 256) fs[c] = feat[b * CHW + c * HW + hw];
    __syncthreads();

    double bv = DBL_MAX; int bi = N_BANK;
    for (int rr = 0; rr < 64; ++rr){
      int j = chunk * 256 + wv * 64 + rr;
      const float* mrow = mb + (size_t)j * K_DIM;
      double s = 0.0;
#pragma unroll
      for (int i = 0; i < 16; ++i){
        int c = lane + i * 64;
        double d = (double)fs[c] - (double)mrow[c];
        s = fma(d, d, s);
      }
#pragma unroll
      for (int off = 1; off < 64; off <<= 1) s += __shfl_xor(s, off);
      if (s < bv){ bv = s; bi = j; }
    }
    if (lane == 0){ wvv[wv] = bv; wvi[wv] = bi; }
    __syncthreads();
    if (threadIdx.x == 0){
      double gv = wvv[0]; int gi2 = wvi[0];
#pragma unroll
      for (int x = 1; x < 4; ++x){
        if (wvv[x] < gv || (wvv[x] == gv && wvi[x] < gi2)){ gv = wvv[x]; gi2 = wvi[x]; }
      }
      rpv[fi * 64 + chunk] = gv; rpi[fi * 64 + chunk] = gi2;
    }
    __syncthreads();
  }
}

// ---------------- kernel C2: combine 64 chunk-partials per refined row ----------------
__global__ __launch_bounds__(256) void refine_combine_kernel(
    const double* __restrict__ rpv, const int* __restrict__ rpi,
    const int* __restrict__ list, const int* __restrict__ cnt, int* __restrict__ sidx)
{
  const int nf = min(*cnt, CAP);
  const int wv = threadIdx.x >> 6, lane = threadIdx.x & 63;
  for (int fi = wv; fi < nf; fi += 4){
    double v = rpv[fi * 64 + lane]; int ii = rpi[fi * 64 + lane];
#pragma unroll
    for (int off = 1; off < 64; off <<= 1){
      double ov = __shfl_xor(v, off); int oi = __shfl_xor(ii, off);
      if (ov < v || (ov == v && oi < ii)){ v = ov; ii = oi; }
    }
    if (lane == 0) sidx[list[fi]] = ii;
  }
}

// ---------------- kernel D: f64 influence from the winner ----------------
__global__ __launch_bounds__(256) void influence_kernel(
    const float* __restrict__ feat, const float* __restrict__ mb,
    const int* __restrict__ sidx, double* __restrict__ infl)
{
  const int wid  = (blockIdx.x * 256 + threadIdx.x) >> 6;
  const int lane = threadIdx.x & 63;
  if (wid >= M_ROWS) return;
  const int r = wid;
  const int b = r / HW;
  const int baseR = b * CHW + (r - b * HW);
  const float* mrow = mb + (size_t)sidx[r] * K_DIM;
  double sabs = 0.0, sd2 = 0.0;
#pragma unroll
  for (int i = 0; i < 16; ++i){
    int c = lane + i*64;
    double d = (double)feat[baseR + c * HW] - (double)mrow[c];
    sd2  = fma(d, d, sd2);
    sabs += fabs(d);
  }
#pragma unroll
  for (int off = 1; off < 64; off <<= 1){
    sabs += __shfl_xor(sabs, off);
    sd2  += __shfl_xor(sd2, off);
  }
  if (lane == 0){
    double dist = sqrt(fmax(sd2, 0.0) + 1e-8);
    infl[r] = (sabs / 1024.0) / (dist + 1e-8);
  }
}

// ---------------- kernel E: f64 global min/max ----------------
__global__ __launch_bounds__(1024) void minmax_kernel(const double* __restrict__ infl, double* __restrict__ mm){
  __shared__ double smn[1024], smx[1024];
  int t = threadIdx.x;
  double mn = DBL_MAX, mx = -DBL_MAX;
  for (int i = t; i < M_ROWS; i += 1024){ double v = infl[i]; mn = fmin(mn, v); mx = fmax(mx, v); }
  smn[t] = mn; smx[t] = mx; __syncthreads();
  for (int off = 512; off > 0; off >>= 1){
    if (t < off){ smn[t] = fmin(smn[t], smn[t+off]); smx[t] = fmax(smx[t], smx[t+off]); }
    __syncthreads();
  }
  if (t == 0){ mm[0] = smn[0]; mm[1] = smx[0]; }
}

// ---------------- kernel F: f64 norm + std -> f32; stash mm into d_ws ----------------
__global__ __launch_bounds__(256) void normstd_kernel(
    const double* __restrict__ mm, const double* __restrict__ infl,
    float* __restrict__ norm_out, float* __restrict__ std_out, double* __restrict__ dws)
{
  int r = blockIdx.x * blockDim.x + threadIdx.x;
  if (r >= M_ROWS) return;
  double imin = mm[0], imax = mm[1];
  if (r == 0){ dws[0] = imin; dws[1] = imax; }
  double rng = imax - imin;
  double nrm = (rng > 1e-8) ? (infl[r] - imin) / rng : 0.0;
  norm_out[r] = (float)nrm;
  std_out[r]  = (float)(0.01 + nrm * 0.49);
}

// ---------------- kernel G: noise — partitionable (0,e), bits = o0 ^ o1 (VERIFIED r9) ------
__global__ __launch_bounds__(256) void noise_kernel(
    const float* __restrict__ feat, const float* __restrict__ stds, float* __restrict__ out)
{
  int tid = blockIdx.x * 256 + threadIdx.x;
  int b   = tid / CHW;
  int rem = tid - b * CHW;
  int c   = rem / HW;
  int hw  = rem - c * HW;
  int r   = b * HW + hw;
  unsigned e = (unsigned)r * (unsigned)K_DIM + (unsigned)c;
  unsigned o0, o1;
  tf2x32(0u, 1u, 0u, e, o0, o1);
  unsigned bits = o0 ^ o1;
  float n = normal_from_bits(bits);
  out[tid] = feat[tid] + n * stds[r];
}

// ---------------- diagnostics (inert when healthy) ----------------
__global__ void diag_kernel(const double* __restrict__ dws, float* __restrict__ out){
  double imin = dws[0], imax = dws[1];
  double rng = imax - imin;
  double code = 0.0, payload = 0.0;
  if (!(imin == imin) || !(imax == imax)){ code = 5e6; }
  else if (rng <= 1e-8){ code = 1e6; payload = fmin(fmax(rng, 0.0) * 1e12, 9e5); }
  else if (imax > 0.5){ code = 2e6; payload = fmin(imax * 1e4, 9e5); }
  else if (imin <= 1e-4){ code = 3e6; payload = fmin(fmax(imin, 0.0) * 1e6, 9e5); }
  else if (imax > 10.0 * imin){ code = 4e6; payload = fmin(imax * 1e4, 9e5); }
  if (code > 0.0) out[0] = (float)(code + payload);
}

__global__ void kat_kernel(float* __restrict__ out){
  float code = 0.f;
  unsigned a, b;
  tf2x32(0u, 0u, 0u, 0u, a, b);
  if (a != 0x6b200159u || b != 0x99ba4efeu) code = 1e10f;
  unsigned c2, d2;
  tf2x32(0x13198a2eu, 0x03707344u, 0x243f6a88u, 0x85a308d3u, c2, d2);
  if (code == 0.f && (c2 != 0xc4923a9cu || d2 != 0x483df7a0u)) code = 3e9f;
  float n = normal_from_bits(0x6b200159u);
  if (code == 0.f && fabsf(n - (-0.20584226f)) > 2e-5f) code = 1e9f;
  if (code > 0.f) out[0] = code;
}

extern "C" void kernel_launch(void* const* d_in, const int* in_sizes, int n_in,
                              void* d_out, int out_size, void* d_ws, size_t ws_size,
                              hipStream_t stream) {
  const float* feat = (const float*)d_in[0];
  const float* mb   = (const float*)d_in[1];
  float* out = (float*)d_out;

  int*    sidx = (int*)(out + WS_SIDX);
  double* infl = (double*)(out + WS_INFL);
  double* mm   = (double*)(out + WS_MM);
  float*  mbn  = out + WS_MBN;
  float*  pb   = out + WS_PB;
  float*  ps   = out + WS_PS;
  int*    pi   = (int*)(out + WS_PI);
  int*    list = (int*)(out + WS_LIST);
  double* rpv  = (double*)(out + WS_RPV);
  int*    rpi  = (int*)(out + WS_RPI);
  unsigned short* fbf = (unsigned short*)(out + WS_FBF);
  double* dws  = (double*)d_ws;
  int*    cnt  = (int*)((char*)d_ws + 16);
  float*  nrm  = out + OUT_NORM_OFF;
  float*  stds = out + OUT_STD_OFF;

  mbnorm_kernel<<<N_BANK/4, 256, 0, stream>>>(mb, mbn);
  init_kernel<<<1, 64, 0, stream>>>(cnt);
  featbf_kernel<<<dim3(49, 8, 8), 256, 0, stream>>>(feat, fbf);
  knn_min_kernel<<<dim3(M_ROWS/128, JSPLIT), 256, 0, stream>>>(fbf, mb, mbn, pb, ps, pi);
  reduce_parts_kernel<<<(M_ROWS + 255)/256, 256, 0, stream>>>(pb, ps, pi, sidx, list, cnt);
  refine_part_kernel<<<2048, 256, 0, stream>>>(feat, mb, list, cnt, rpv, rpi);
  refine_combine_kernel<<<1, 256, 0, stream>>>(rpv, rpi, list, cnt, sidx);
  influence_kernel<<<(M_ROWS*64)/256, 256, 0, stream>>>(feat, mb, sidx, infl);
  minmax_kernel<<<1, 1024, 0, stream>>>(infl, mm);
  normstd_kernel<<<(M_ROWS + 255)/256, 256, 0, stream>>>(mm, infl, nrm, stds, dws);
  noise_kernel<<<N_ELEMS/256, 256, 0, stream>>>(feat, stds, out);
  diag_kernel<<<1, 1, 0, stream>>>(dws, out);
  kat_kernel<<<1, 1, 0, stream>>>(out);
}